// Round 11
// baseline (298.247 us; speedup 1.0000x reference)
//
#include <hip/hip_runtime.h>
#include <math.h>

#define D 256
#define B 16
#define L 8
#define N 128

static constexpr float LAMBDA_ASYNC = 0.08f;
static constexpr float LAMBDA_TAU   = 0.12f;

// ws layout (floats) — single rotating buffers (stream strictly serial):
//   acct[4096]   @ 0      (pre-scaled vin for next layer, [d][b]; xt for l==0)
//   colsum[256]  @ 4096   (per-d column sums of CURRENT vin)
//   meta[16]     @ 4352   (meta[0] = fired count of previous layer)
//   fired[128]   @ 4368
//   slab[N][NQ][4096] @ 4496  (raw d-partial sums, NO tanh/bias)
// NQ chosen from ws_size at launch: 4 (8.4 MB), 2 (4.2 MB), 1 (2.1 MB).

#define OFF_COLSUM 4096
#define OFF_META   4352
#define OFF_FIRED  4368
#define OFF_SLAB   4496

__device__ __forceinline__ float4 fma4(float s, float4 w, float4 a) {
    a.x = fmaf(s, w.x, a.x); a.y = fmaf(s, w.y, a.y);
    a.z = fmaf(s, w.z, a.z); a.w = fmaf(s, w.w, a.w);
    return a;
}

// X[b][d] -> xt[d][b]; colsum0[d] = sum_b X[b][d]
__global__ __launch_bounds__(256) void transpose_kernel(
    const float* __restrict__ X, float* __restrict__ xt,
    float* __restrict__ colsum) {
    const int d = threadIdx.x;
    float cs = 0.0f;
    #pragma unroll
    for (int b = 0; b < B; ++b) {
        const float v = X[b * D + d];
        xt[d * 16 + b] = v;
        cs += v;
    }
    colsum[d] = cs;
}

// Grid: N*NQ blocks = (node n, d-slice q). Block: 256 thr = 4 waves.
// Block d-range DR = 256/NQ; wave owns WR = DR/4 rows; lane owns e-quad
// e = 4*lane..4*lane+3 (full 256 e per wave).
// Per d-row: 1 global_load_dwordx4 (W, 1 KB/wave) + 4 broadcast ds_read_b128
// + 16 vector-FMA4. Raw partials -> slab (no bias/tanh here, no atomics).
template<int NQ>
__global__ __launch_bounds__(256, 4) void layer_kernel(
    const float* __restrict__ Wl,         // N*D*D (this layer)
    const float* __restrict__ Sl,         // N*D
    const float* __restrict__ rhol,       // N
    const float* __restrict__ boostl,     // N
    const int*  __restrict__ tb,
    const float* __restrict__ vin_src,    // [d][b] PRE-SCALED (xt for l==0)
    const float* __restrict__ colsum,     // [256]
    const float* __restrict__ meta_prev,  // null if l==0
    float* __restrict__ slab,             // [n][NQ][4096] raw partials
    float* __restrict__ fired_cur,        // N
    float depth)
{
    constexpr int DR = 256 / NQ;          // d-rows per block
    constexpr int WR = DR / 4;            // d-rows per wave

    __shared__ float vin[DR * 16];        // [d_local][b], up to 16 KB (NQ=1)
    __shared__ float red[2][16][256];     // [slot][b][e], 32 KB
    __shared__ float sh[4];

    const int t    = threadIdx.x;
    const int w    = t >> 6;
    const int lane = t & 63;
    const int n    = blockIdx.x / NQ;
    const int q    = blockIdx.x - n * NQ;

    // ---- firing preamble from global colsum (1 KB) — before any staging
    float part = colsum[t] * Sl[n * D + t];
    #pragma unroll
    for (int o = 32; o > 0; o >>= 1) part += __shfl_down(part, o);
    if (lane == 0) sh[w] = part;
    __syncthreads();
    {
        const bool has_input = (meta_prev == nullptr) ? true : (meta_prev[0] > 0.0f);
        const float sdot = (sh[0] + sh[1] + sh[2] + sh[3]) * (1.0f / 16.0f);
        const float tau  = 0.5f * expf(LAMBDA_TAU * (depth - (float)tb[0]));
        const bool fired = (rhol[n] + sdot + boostl[n] >= tau) && has_input;
        if (q == 0 && t == 0) fired_cur[n] = fired ? 1.0f : 0.0f;
        if (!fired) return;   // block-uniform: skip staging + W stream + store
    }

    // ---- stage this block's d-slice of vin into LDS (DR*16 floats)
    {
        const float4* s4 = (const float4*)(vin_src + q * DR * 16);
        #pragma unroll
        for (int k = 0; k < DR / 64; ++k)
            ((float4*)vin)[t + k * 256] = s4[t + k * 256];
    }
    __syncthreads();

    // ---- main loop: WR d-rows, 2-row ping-pong W prefetch
    const int d0 = q * DR + w * WR;
    const float* wp = Wl + ((size_t)n * D + (size_t)d0) * D + 4 * lane;

    float4 accv[16];
    #pragma unroll
    for (int b = 0; b < 16; ++b) accv[b] = make_float4(0.f, 0.f, 0.f, 0.f);

    float4 wbuf[2][2];
    wbuf[0][0] = *(const float4*)(wp + (size_t)0 * D);
    wbuf[0][1] = *(const float4*)(wp + (size_t)1 * D);

    #pragma unroll
    for (int c = 0; c < WR / 2; ++c) {
        const int pb = c & 1, nb = pb ^ 1;
        if (c < WR / 2 - 1) {
            wbuf[nb][0] = *(const float4*)(wp + (size_t)(2 * c + 2) * D);
            wbuf[nb][1] = *(const float4*)(wp + (size_t)(2 * c + 3) * D);
        }
        #pragma unroll
        for (int r = 0; r < 2; ++r) {
            const float* vr = &vin[(w * WR + 2 * c + r) * 16];
            const float4 vA = *(const float4*)(vr + 0);
            const float4 vB = *(const float4*)(vr + 4);
            const float4 vC = *(const float4*)(vr + 8);
            const float4 vD = *(const float4*)(vr + 12);
            const float4 wv = wbuf[pb][r];
            accv[ 0] = fma4(vA.x, wv, accv[ 0]);
            accv[ 1] = fma4(vA.y, wv, accv[ 1]);
            accv[ 2] = fma4(vA.z, wv, accv[ 2]);
            accv[ 3] = fma4(vA.w, wv, accv[ 3]);
            accv[ 4] = fma4(vB.x, wv, accv[ 4]);
            accv[ 5] = fma4(vB.y, wv, accv[ 5]);
            accv[ 6] = fma4(vB.z, wv, accv[ 6]);
            accv[ 7] = fma4(vB.w, wv, accv[ 7]);
            accv[ 8] = fma4(vC.x, wv, accv[ 8]);
            accv[ 9] = fma4(vC.y, wv, accv[ 9]);
            accv[10] = fma4(vC.z, wv, accv[10]);
            accv[11] = fma4(vC.w, wv, accv[11]);
            accv[12] = fma4(vD.x, wv, accv[12]);
            accv[13] = fma4(vD.y, wv, accv[13]);
            accv[14] = fma4(vD.z, wv, accv[14]);
            accv[15] = fma4(vD.w, wv, accv[15]);
        }
    }

    // ---- in-block d-reduce: waves 2,3 write slots 0,1; waves 0,1 add in.
    // All accesses lane-consecutive b128 -> conflict-free.
    if (w >= 2) {
        #pragma unroll
        for (int b = 0; b < 16; ++b)
            *(float4*)&red[w - 2][b][4 * lane] = accv[b];
    }
    __syncthreads();
    if (w < 2) {
        #pragma unroll
        for (int b = 0; b < 16; ++b) {
            float4 o = *(const float4*)&red[w][b][4 * lane];
            o.x += accv[b].x; o.y += accv[b].y;
            o.z += accv[b].z; o.w += accv[b].w;
            *(float4*)&red[w][b][4 * lane] = o;
        }
    }
    __syncthreads();

    // ---- epilogue: thread t = e; p[b] = slot0+slot1; coalesced 64 B store
    {
        const int e = t;
        float* dst = slab + ((size_t)(n * NQ + q)) * 4096 + (size_t)e * 16;
        #pragma unroll
        for (int b4 = 0; b4 < 4; ++b4) {
            float4 o;
            o.x = red[0][b4 * 4 + 0][e] + red[1][b4 * 4 + 0][e];
            o.y = red[0][b4 * 4 + 1][e] + red[1][b4 * 4 + 1][e];
            o.z = red[0][b4 * 4 + 2][e] + red[1][b4 * 4 + 2][e];
            o.w = red[0][b4 * 4 + 3][e] + red[1][b4 * 4 + 3][e];
            *(float4*)(dst + b4 * 4) = o;
        }
    }
}

// 64 blocks x 256 thr; thread = (cell, n-chunk of 32).
// acct[c] = scale * sum_n fired[n] * tanh(sum_q slab[n][q][c] + bias[n][e])
// colsum[d] = sum_b acct; meta = cnt.  (IS_FINAL: out[b][e] = .../cnt)
template<int NQ, bool IS_FINAL>
__global__ __launch_bounds__(256) void reduce_kernel(
    const float* __restrict__ slab, const float* __restrict__ biasl,
    const float* __restrict__ fired_l,
    float* __restrict__ acct, float* __restrict__ colsum,
    float* __restrict__ meta, float* __restrict__ out)
{
    __shared__ float part[256];
    __shared__ float shcnt;
    const int t    = threadIdx.x;
    const int cell = blockIdx.x * 64 + (t & 63);
    const int n0   = (t >> 6) * 32;
    const int e    = cell >> 4;

    float s = 0.0f;
    for (int k = 0; k < 32; ++k) {
        const int n = n0 + k;
        const float f = fired_l[n];
        if (f > 0.0f) {                       // wave-uniform branch
            float p = 0.0f;
            #pragma unroll
            for (int qq = 0; qq < NQ; ++qq)
                p += slab[((size_t)(n * NQ + qq)) * 4096 + cell];
            s += tanhf(p + biasl[n * D + e]);
        }
    }
    part[t] = s;

    if (t < 64) {                             // wave 0: fired count
        float c = fired_l[t] + fired_l[t + 64];
        #pragma unroll
        for (int o = 32; o > 0; o >>= 1) c += __shfl_down(c, o);
        if (t == 0) shcnt = c;
    }
    __syncthreads();

    if (t < 64) {
        const float cnt = shcnt;
        const int c = blockIdx.x * 64 + t;
        const float tot = part[t] + part[64 + t] + part[128 + t] + part[192 + t];
        if (IS_FINAL) {
            const float v = tot / fmaxf(cnt, 1.0f);
            out[(c & 15) * 256 + (c >> 4)] = v;   // out[b][e]
        } else {
            const float scale = expf(-LAMBDA_ASYNC) / fmaxf(cnt, 1.0f);
            const float v = tot * scale;
            acct[c] = v;
            float cs = v;                          // colsum over 16 b's per d
            cs += __shfl_down(cs, 8);
            cs += __shfl_down(cs, 4);
            cs += __shfl_down(cs, 2);
            cs += __shfl_down(cs, 1);
            if ((t & 15) == 0) colsum[c >> 4] = cs;
            if (blockIdx.x == 0 && t == 0) meta[0] = cnt;
        }
    }
}

template<int NQ>
static void run_pipeline(const float* X, const float* W, const float* bias,
                         const float* S, const float* rho, const float* boost,
                         const int* tb, float* out, float* ws, hipStream_t stream)
{
    float* acct   = ws;
    float* colsum = ws + OFF_COLSUM;
    float* meta   = ws + OFF_META;
    float* fired  = ws + OFF_FIRED;
    float* slab   = ws + OFF_SLAB;

    transpose_kernel<<<dim3(1), dim3(256), 0, stream>>>(X, acct, colsum);

    for (int l = 0; l < L; ++l) {
        layer_kernel<NQ><<<dim3(N * NQ), dim3(256), 0, stream>>>(
            W + (size_t)l * N * D * D,
            S + (size_t)l * N * D,
            rho + (size_t)l * N,
            boost + (size_t)l * N,
            tb,
            acct, colsum,
            (l == 0) ? (const float*)nullptr : meta,
            slab, fired, (float)(l + 1));
        if (l < L - 1) {
            reduce_kernel<NQ, false><<<dim3(64), dim3(256), 0, stream>>>(
                slab, bias + (size_t)l * N * D, fired,
                acct, colsum, meta, out);
        } else {
            reduce_kernel<NQ, true><<<dim3(64), dim3(256), 0, stream>>>(
                slab, bias + (size_t)l * N * D, fired,
                acct, colsum, meta, out);
        }
    }
}

extern "C" void kernel_launch(void* const* d_in, const int* in_sizes, int n_in,
                              void* d_out, int out_size, void* d_ws, size_t ws_size,
                              hipStream_t stream)
{
    const float* X     = (const float*)d_in[0];
    const float* W     = (const float*)d_in[1];
    const float* bias  = (const float*)d_in[2];
    const float* S     = (const float*)d_in[3];
    const float* rho   = (const float*)d_in[4];
    const float* boost = (const float*)d_in[5];
    const int*   tb    = (const int*)d_in[6];
    float* out = (float*)d_out;
    float* ws  = (float*)d_ws;

    const size_t need4 = (size_t)(OFF_SLAB + N * 4 * 4096) * sizeof(float);
    const size_t need2 = (size_t)(OFF_SLAB + N * 2 * 4096) * sizeof(float);

    if (ws_size >= need4)
        run_pipeline<4>(X, W, bias, S, rho, boost, tb, out, ws, stream);
    else if (ws_size >= need2)
        run_pipeline<2>(X, W, bias, S, rho, boost, tb, out, ws, stream);
    else
        run_pipeline<1>(X, W, bias, S, rho, boost, tb, out, ws, stream);
}

// Round 12
// 285.367 us; speedup vs baseline: 1.0451x; 1.0451x over previous
//
#include <hip/hip_runtime.h>
#include <math.h>

#define D 256
#define B 16
#define L 8
#define N 128

static constexpr float LAMBDA_ASYNC = 0.08f;
static constexpr float LAMBDA_TAU   = 0.12f;

// ws layout (floats) — single rotating buffers (stream strictly serial):
//   acct[4096]   @ 0      (pre-scaled vin for next layer, [d][b]; xt for l==0)
//   colsum[256]  @ 4096   (per-d column sums of CURRENT vin)
//   meta[16]     @ 4352   (meta[0] = fired count of previous layer)
//   fired[128]   @ 4368
//   slab[N][NQ][4096] @ 4496  (raw d-partial sums, NO tanh/bias)
// NQ chosen from ws_size at launch: 4 (8.4 MB), 2 (4.2 MB), 1 (2.1 MB).

#define OFF_COLSUM 4096
#define OFF_META   4352
#define OFF_FIRED  4368
#define OFF_SLAB   4496

__device__ __forceinline__ float4 fma4(float s, float4 w, float4 a) {
    a.x = fmaf(s, w.x, a.x); a.y = fmaf(s, w.y, a.y);
    a.z = fmaf(s, w.z, a.z); a.w = fmaf(s, w.w, a.w);
    return a;
}

// X[b][d] -> xt[d][b]; colsum0[d] = sum_b X[b][d]
__global__ __launch_bounds__(256) void transpose_kernel(
    const float* __restrict__ X, float* __restrict__ xt,
    float* __restrict__ colsum) {
    const int d = threadIdx.x;
    float cs = 0.0f;
    #pragma unroll
    for (int b = 0; b < B; ++b) {
        const float v = X[b * D + d];
        xt[d * 16 + b] = v;
        cs += v;
    }
    colsum[d] = cs;
}

// Grid: N*NQ blocks = (node n, d-slice q). Block: 256 thr = 4 waves.
// Block d-range DR = 256/NQ; wave owns WR = DR/4 rows; lane owns e-quad
// e = 4*lane..4*lane+3 (full 256 e per wave).
// Per d-row: 1 global_load_dwordx4 (W, 1 KB/wave) + 4 broadcast ds_read_b128
// + 16 vector-FMA4. Raw partials -> slab. NO launch_bounds min-occupancy:
// accv[16]x4 = 64 VGPR; a 128-reg cap spills (R11 regression, 298 us).
template<int NQ>
__global__ __launch_bounds__(256) void layer_kernel(
    const float* __restrict__ Wl,         // N*D*D (this layer)
    const float* __restrict__ Sl,         // N*D
    const float* __restrict__ rhol,       // N
    const float* __restrict__ boostl,     // N
    const int*  __restrict__ tb,
    const float* __restrict__ vin_src,    // [d][b] PRE-SCALED (xt for l==0)
    const float* __restrict__ colsum,     // [256]
    const float* __restrict__ meta_prev,  // null if l==0
    float* __restrict__ slab,             // [n][NQ][4096] raw partials
    float* __restrict__ fired_cur,        // N
    float depth)
{
    constexpr int DR = 256 / NQ;          // d-rows per block
    constexpr int WR = DR / 4;            // d-rows per wave

    __shared__ float vin[DR * 16];        // [d_local][b]
    __shared__ float red[2][16][256];     // [slot][b][e], 32 KB
    __shared__ float sh[4];

    const int t    = threadIdx.x;
    const int w    = t >> 6;
    const int lane = t & 63;
    const int n    = blockIdx.x / NQ;
    const int q    = blockIdx.x - n * NQ;

    // ---- firing preamble from global colsum (1 KB) — before any staging
    float part = colsum[t] * Sl[n * D + t];
    #pragma unroll
    for (int o = 32; o > 0; o >>= 1) part += __shfl_down(part, o);
    if (lane == 0) sh[w] = part;
    __syncthreads();
    {
        const bool has_input = (meta_prev == nullptr) ? true : (meta_prev[0] > 0.0f);
        const float sdot = (sh[0] + sh[1] + sh[2] + sh[3]) * (1.0f / 16.0f);
        const float tau  = 0.5f * expf(LAMBDA_TAU * (depth - (float)tb[0]));
        const bool fired = (rhol[n] + sdot + boostl[n] >= tau) && has_input;
        if (q == 0 && t == 0) fired_cur[n] = fired ? 1.0f : 0.0f;
        if (!fired) return;   // block-uniform: skip staging + W stream + store
    }

    // ---- stage this block's d-slice of vin into LDS (DR*16 floats)
    {
        const float4* s4 = (const float4*)(vin_src + q * DR * 16);
        #pragma unroll
        for (int k = 0; k < DR / 64; ++k)
            ((float4*)vin)[t + k * 256] = s4[t + k * 256];
    }
    __syncthreads();

    // ---- main loop: WR d-rows; unroll 4 keeps ~4 W-loads in flight
    const int d0 = q * DR + w * WR;
    const float* wp = Wl + ((size_t)n * D + (size_t)d0) * D + 4 * lane;

    float4 accv[16];
    #pragma unroll
    for (int b = 0; b < 16; ++b) accv[b] = make_float4(0.f, 0.f, 0.f, 0.f);

    #pragma unroll 4
    for (int r = 0; r < WR; ++r) {
        const float4 wv = *(const float4*)(wp + (size_t)r * D);
        const float* vr = &vin[(w * WR + r) * 16];
        const float4 vA = *(const float4*)(vr + 0);
        const float4 vB = *(const float4*)(vr + 4);
        const float4 vC = *(const float4*)(vr + 8);
        const float4 vD = *(const float4*)(vr + 12);
        accv[ 0] = fma4(vA.x, wv, accv[ 0]);
        accv[ 1] = fma4(vA.y, wv, accv[ 1]);
        accv[ 2] = fma4(vA.z, wv, accv[ 2]);
        accv[ 3] = fma4(vA.w, wv, accv[ 3]);
        accv[ 4] = fma4(vB.x, wv, accv[ 4]);
        accv[ 5] = fma4(vB.y, wv, accv[ 5]);
        accv[ 6] = fma4(vB.z, wv, accv[ 6]);
        accv[ 7] = fma4(vB.w, wv, accv[ 7]);
        accv[ 8] = fma4(vC.x, wv, accv[ 8]);
        accv[ 9] = fma4(vC.y, wv, accv[ 9]);
        accv[10] = fma4(vC.z, wv, accv[10]);
        accv[11] = fma4(vC.w, wv, accv[11]);
        accv[12] = fma4(vD.x, wv, accv[12]);
        accv[13] = fma4(vD.y, wv, accv[13]);
        accv[14] = fma4(vD.z, wv, accv[14]);
        accv[15] = fma4(vD.w, wv, accv[15]);
    }

    // ---- in-block d-reduce: waves 2,3 write slots 0,1; waves 0,1 add in.
    // All accesses lane-consecutive b128 -> conflict-free.
    if (w >= 2) {
        #pragma unroll
        for (int b = 0; b < 16; ++b)
            *(float4*)&red[w - 2][b][4 * lane] = accv[b];
    }
    __syncthreads();
    if (w < 2) {
        #pragma unroll
        for (int b = 0; b < 16; ++b) {
            float4 o = *(const float4*)&red[w][b][4 * lane];
            o.x += accv[b].x; o.y += accv[b].y;
            o.z += accv[b].z; o.w += accv[b].w;
            *(float4*)&red[w][b][4 * lane] = o;
        }
    }
    __syncthreads();

    // ---- epilogue: thread t = e; p[b] = slot0+slot1; coalesced 64 B store
    {
        const int e = t;
        float* dst = slab + ((size_t)(n * NQ + q)) * 4096 + (size_t)e * 16;
        #pragma unroll
        for (int b4 = 0; b4 < 4; ++b4) {
            float4 o;
            o.x = red[0][b4 * 4 + 0][e] + red[1][b4 * 4 + 0][e];
            o.y = red[0][b4 * 4 + 1][e] + red[1][b4 * 4 + 1][e];
            o.z = red[0][b4 * 4 + 2][e] + red[1][b4 * 4 + 2][e];
            o.w = red[0][b4 * 4 + 3][e] + red[1][b4 * 4 + 3][e];
            *(float4*)(dst + b4 * 4) = o;
        }
    }
}

// 64 blocks x 256 thr; thread = (cell, n-chunk of 32).
// acct[c] = scale * sum_n fired[n] * tanh(sum_q slab[n][q][c] + bias[n][e])
// colsum[d] = sum_b acct; meta = cnt.  (IS_FINAL: out[b][e] = .../cnt)
template<int NQ, bool IS_FINAL>
__global__ __launch_bounds__(256) void reduce_kernel(
    const float* __restrict__ slab, const float* __restrict__ biasl,
    const float* __restrict__ fired_l,
    float* __restrict__ acct, float* __restrict__ colsum,
    float* __restrict__ meta, float* __restrict__ out)
{
    __shared__ float part[256];
    __shared__ float shcnt;
    const int t    = threadIdx.x;
    const int cell = blockIdx.x * 64 + (t & 63);
    const int n0   = (t >> 6) * 32;
    const int e    = cell >> 4;

    float s = 0.0f;
    for (int k = 0; k < 32; ++k) {
        const int n = n0 + k;
        const float f = fired_l[n];
        if (f > 0.0f) {                       // wave-uniform branch
            float p = 0.0f;
            #pragma unroll
            for (int qq = 0; qq < NQ; ++qq)
                p += slab[((size_t)(n * NQ + qq)) * 4096 + cell];
            s += tanhf(p + biasl[n * D + e]);
        }
    }
    part[t] = s;

    if (t < 64) {                             // wave 0: fired count
        float c = fired_l[t] + fired_l[t + 64];
        #pragma unroll
        for (int o = 32; o > 0; o >>= 1) c += __shfl_down(c, o);
        if (t == 0) shcnt = c;
    }
    __syncthreads();

    if (t < 64) {
        const float cnt = shcnt;
        const int c = blockIdx.x * 64 + t;
        const float tot = part[t] + part[64 + t] + part[128 + t] + part[192 + t];
        if (IS_FINAL) {
            const float v = tot / fmaxf(cnt, 1.0f);
            out[(c & 15) * 256 + (c >> 4)] = v;   // out[b][e]
        } else {
            const float scale = expf(-LAMBDA_ASYNC) / fmaxf(cnt, 1.0f);
            const float v = tot * scale;
            acct[c] = v;
            float cs = v;                          // colsum over 16 b's per d
            cs += __shfl_down(cs, 8);
            cs += __shfl_down(cs, 4);
            cs += __shfl_down(cs, 2);
            cs += __shfl_down(cs, 1);
            if ((t & 15) == 0) colsum[c >> 4] = cs;
            if (blockIdx.x == 0 && t == 0) meta[0] = cnt;
        }
    }
}

template<int NQ>
static void run_pipeline(const float* X, const float* W, const float* bias,
                         const float* S, const float* rho, const float* boost,
                         const int* tb, float* out, float* ws, hipStream_t stream)
{
    float* acct   = ws;
    float* colsum = ws + OFF_COLSUM;
    float* meta   = ws + OFF_META;
    float* fired  = ws + OFF_FIRED;
    float* slab   = ws + OFF_SLAB;

    transpose_kernel<<<dim3(1), dim3(256), 0, stream>>>(X, acct, colsum);

    for (int l = 0; l < L; ++l) {
        layer_kernel<NQ><<<dim3(N * NQ), dim3(256), 0, stream>>>(
            W + (size_t)l * N * D * D,
            S + (size_t)l * N * D,
            rho + (size_t)l * N,
            boost + (size_t)l * N,
            tb,
            acct, colsum,
            (l == 0) ? (const float*)nullptr : meta,
            slab, fired, (float)(l + 1));
        if (l < L - 1) {
            reduce_kernel<NQ, false><<<dim3(64), dim3(256), 0, stream>>>(
                slab, bias + (size_t)l * N * D, fired,
                acct, colsum, meta, out);
        } else {
            reduce_kernel<NQ, true><<<dim3(64), dim3(256), 0, stream>>>(
                slab, bias + (size_t)l * N * D, fired,
                acct, colsum, meta, out);
        }
    }
}

extern "C" void kernel_launch(void* const* d_in, const int* in_sizes, int n_in,
                              void* d_out, int out_size, void* d_ws, size_t ws_size,
                              hipStream_t stream)
{
    const float* X     = (const float*)d_in[0];
    const float* W     = (const float*)d_in[1];
    const float* bias  = (const float*)d_in[2];
    const float* S     = (const float*)d_in[3];
    const float* rho   = (const float*)d_in[4];
    const float* boost = (const float*)d_in[5];
    const int*   tb    = (const int*)d_in[6];
    float* out = (float*)d_out;
    float* ws  = (float*)d_ws;

    const size_t need4 = (size_t)(OFF_SLAB + N * 4 * 4096) * sizeof(float);
    const size_t need2 = (size_t)(OFF_SLAB + N * 2 * 4096) * sizeof(float);

    if (ws_size >= need4)
        run_pipeline<4>(X, W, bias, S, rho, boost, tb, out, ws, stream);
    else if (ws_size >= need2)
        run_pipeline<2>(X, W, bias, S, rho, boost, tb, out, ws, stream);
    else
        run_pipeline<1>(X, W, bias, S, rho, boost, tb, out, ws, stream);
}